// Round 7
// baseline (1139.249 us; speedup 1.0000x reference)
//
#include <hip/hip_runtime.h>
#include <cstdint>

#define DIMD 256
#define KCB  4096
#define NQ   4
#define NTOK 32768   // 8 * 4096

typedef __attribute__((ext_vector_type(8))) _Float16 half8;
typedef __attribute__((ext_vector_type(4))) _Float16 half4;
typedef __attribute__((ext_vector_type(4))) float f32x4;

// ---------------------------------------------------------------- helpers
__device__ __forceinline__ f32x4 mfma16(half8 a, half8 b, f32x4 c) {
  return __builtin_amdgcn_mfma_f32_16x16x32_f16(a, b, c, 0, 0, 0);
}

// ---------------------------------------------------------------- prep
// At is ROW-MAJOR fp16 [NTOK][256]: init and post's emit are fully
// coalesced; argmin does the MFMA fragment gather on its once-per-kernel
// A-load (amortized over 64 tiles).
__global__ void init_kernel(const float* __restrict__ x,
                            _Float16* __restrict__ At) {
  const int tid = threadIdx.x;
  const int n = blockIdx.x * 8 + (tid >> 5);
  const int t = tid & 31;
  const size_t base = (size_t)n * DIMD + t * 8;
  const float4 v0 = *(const float4*)&x[base];
  const float4 v1 = *(const float4*)&x[base + 4];
  const float f[8] = {v0.x, v0.y, v0.z, v0.w, v1.x, v1.y, v1.z, v1.w};
  half8 h;
  #pragma unroll
  for (int j = 0; j < 8; ++j) h[j] = (_Float16)f[j];
  *(half8*)&At[base] = h;
}

// B plane frag-linear, 64-col-chunk-major (one 64-col chunk = contiguous 32 KB):
// frag f = ((c>>6)*8 + kc)*4 + ((c>>4)&3); half = (f*64 + q*16 + (c&15))*8 + j.
// hcS[c] = 512 + 0.5*|cb_c|^2  (argmin key offset; d' = hcS - dot > 0 always).
__global__ void cb_prep_kernel(const float* __restrict__ cbs,
                               _Float16* __restrict__ Bt,
                               float* __restrict__ hcS) {
  const int tid = threadIdx.x;
  const int R = blockIdx.x * 8 + (tid >> 5);   // layer*4096 + code
  const int layer = R >> 12, c = R & 4095;
  const int t = tid & 31;
  const size_t base = (size_t)R * DIMD + t * 8;
  const float4 v0 = *(const float4*)&cbs[base];
  const float4 v1 = *(const float4*)&cbs[base + 4];
  const float f[8] = {v0.x, v0.y, v0.z, v0.w, v1.x, v1.y, v1.z, v1.w};
  half8 h;
  float s = 0.f;
  #pragma unroll
  for (int j = 0; j < 8; ++j) { h[j] = (_Float16)f[j]; s += f[j] * f[j]; }
  const int kc = t >> 2, q = t & 3;
  _Float16* BtL = Bt + (size_t)layer * KCB * DIMD;
  const int fr = ((c >> 6) * 8 + kc) * 4 + ((c >> 4) & 3);
  *(half8*)&BtL[((size_t)fr * 64 + q * 16 + (c & 15)) * 8] = h;
  #pragma unroll
  for (int off = 16; off > 0; off >>= 1) s += __shfl_down(s, off, 32);
  if (t == 0) hcS[R] = 512.0f + 0.5f * s;
}

// ---------------------------------------------------------------- argmin
// A resident in registers (64 rows x 256 d per wave, gathered once from the
// row-major At); B streamed directly from L2 into registers, DEPTH-2
// software pipeline: four named half-tile buffers (pa/qa = even tile,
// pb/qb = odd tile), refills issued one full tile period (~1200 cyc) before
// use so the ~250-cyc L2 latency is fully hidden (depth-1 issued only
// ~300 cyc ahead -> vmcnt stall at every tile boundary, MfmaUtil capped
// at ~38%). No LDS for B, no barriers in the main loop.
__device__ __forceinline__ void upd_keys(const f32x4 (&acc)[4], int tl,
                                         const float* __restrict__ hcs, int ln,
                                         uint32_t* __restrict__ u1,
                                         uint32_t* __restrict__ u2) {
  const float hcv = hcs[tl * 16 + ln];
  #pragma unroll
  for (int rt = 0; rt < 4; ++rt)
    #pragma unroll
    for (int reg = 0; reg < 4; ++reg) {
      const uint32_t k =
          (__float_as_uint(hcv - acc[rt][reg]) & 0xFFFFFFC0u) | (uint32_t)tl;
      const int s = rt * 4 + reg;
      const uint32_t mx = u1[s] > k ? u1[s] : k;
      u1[s] = u1[s] < k ? u1[s] : k;
      u2[s] = u2[s] < mx ? u2[s] : mx;
    }
}

// 16 MFMAs consuming one half-tile buffer (kc0 = 0 or 4); INIT zero-inits acc.
template <bool INIT>
__device__ __forceinline__ void half_mfma(f32x4 (&acc)[4],
                                          const half8 (&a)[4][8],
                                          const half8 (&b)[4], int kc0) {
  __builtin_amdgcn_s_setprio(1);
  if constexpr (INIT) {
    const f32x4 z = {0.f, 0.f, 0.f, 0.f};
    acc[0] = mfma16(a[0][kc0], b[0], z);
    acc[1] = mfma16(a[1][kc0], b[0], z);
    acc[2] = mfma16(a[2][kc0], b[0], z);
    acc[3] = mfma16(a[3][kc0], b[0], z);
  } else {
    #pragma unroll
    for (int rt = 0; rt < 4; ++rt)
      acc[rt] = mfma16(a[rt][kc0], b[0], acc[rt]);
  }
  #pragma unroll
  for (int kc = 1; kc < 4; ++kc)
    #pragma unroll
    for (int rt = 0; rt < 4; ++rt)
      acc[rt] = mfma16(a[rt][kc0 + kc], b[kc], acc[rt]);
  __builtin_amdgcn_s_setprio(0);
}

__global__ __launch_bounds__(256, 2) void argmin_kernel(
    const _Float16* __restrict__ At,     // row-major [NTOK][256]
    const _Float16* __restrict__ Bt,     // layer base (chunk-major frag-linear)
    const float* __restrict__ hcS,       // layer base
    uint2* __restrict__ part)            // [NTOK][4] best-2 col indices
{
  __shared__ float hcs[1024];

  const int tid = threadIdx.x;
  const int lane = tid & 63, w = tid >> 6;   // 4 waves
  const int rg   = blockIdx.x & 127;         // stride-128 siblings share rows
  const int colQ = blockIdx.x >> 7;
  const int quad = lane >> 4, ln = lane & 15;

  // stage hcS quarter to LDS (1024 floats)
  *(float4*)&hcs[tid * 4] = *(const float4*)&hcS[colQ * 1024 + tid * 4];

  // upfront A fragment gather from row-major At:
  // a[rt][kc][j] = A[rb16+rt tile, row ln][kc*32 + quad*8 + j]
  const int rb16 = rg * 16 + w * 4;
  half8 a[4][8];
  #pragma unroll
  for (int kc = 0; kc < 8; ++kc)
    #pragma unroll
    for (int rt = 0; rt < 4; ++rt)
      a[rt][kc] = *(const half8*)&At[((size_t)(rb16 + rt) * 16 + ln) * DIMD +
                                     kc * 32 + quad * 8];

  // best-2 keys per element (16 rows/lane): key = trunc6(as_uint(d')) | tile
  uint32_t u1[16], u2[16];
  #pragma unroll
  for (int s = 0; s < 16; ++s) { u1[s] = 0xFFFFFFFFu; u2[s] = 0xFFFFFFFFu; }

  // quarter base: colQ*1024 cols * 256 d = colQ * 262144 halves
  const _Float16* Bq = Bt + (size_t)colQ * 262144 + lane * 8;
  // frag address for (tile t, kc): ((t>>2)*8 + kc)*4 + (t&3), 512 halves each
  #define BFRAG(t, kc) \
    (*(const half8*)&Bq[(size_t)((((t) >> 2) * 8 + (kc)) * 4 + ((t) & 3)) * 512])

  half8 pa[4], qa[4], pb[4], qb[4];
  #pragma unroll
  for (int k = 0; k < 4; ++k) pa[k] = BFRAG(0, k);
  #pragma unroll
  for (int k = 0; k < 4; ++k) qa[k] = BFRAG(0, 4 + k);
  #pragma unroll
  for (int k = 0; k < 4; ++k) pb[k] = BFRAG(1, k);
  #pragma unroll
  for (int k = 0; k < 4; ++k) qb[k] = BFRAG(1, 4 + k);

  __syncthreads();   // hcs ready (only barrier in the kernel)

  f32x4 accA[4], accB[4];

  // ---- pair (0,1) peeled: no keys for tile -1
  half_mfma<true >(accA, a, pa, 0);
  #pragma unroll
  for (int k = 0; k < 4; ++k) pa[k] = BFRAG(2, k);
  half_mfma<false>(accA, a, qa, 4);
  #pragma unroll
  for (int k = 0; k < 4; ++k) qa[k] = BFRAG(2, 4 + k);
  upd_keys(accA, 0, hcs, ln, u1, u2);
  half_mfma<true >(accB, a, pb, 0);
  #pragma unroll
  for (int k = 0; k < 4; ++k) pb[k] = BFRAG(3, k);
  half_mfma<false>(accB, a, qb, 4);
  #pragma unroll
  for (int k = 0; k < 4; ++k) qb[k] = BFRAG(3, 4 + k);

  // ---- steady pairs t = 2,4,..,62 (branch-free body; refills 2 tiles ahead,
  // wrap mask keeps the final dead refills in-bounds)
  for (int t = 2; t < 64; t += 2) {
    const int t2 = (t + 2) & 63, t3 = (t + 3) & 63;
    upd_keys(accB, t - 1, hcs, ln, u1, u2);
    half_mfma<true >(accA, a, pa, 0);
    #pragma unroll
    for (int k = 0; k < 4; ++k) pa[k] = BFRAG(t2, k);
    half_mfma<false>(accA, a, qa, 4);
    #pragma unroll
    for (int k = 0; k < 4; ++k) qa[k] = BFRAG(t2, 4 + k);
    upd_keys(accA, t, hcs, ln, u1, u2);
    half_mfma<true >(accB, a, pb, 0);
    #pragma unroll
    for (int k = 0; k < 4; ++k) pb[k] = BFRAG(t3, k);
    half_mfma<false>(accB, a, qb, 4);
    #pragma unroll
    for (int k = 0; k < 4; ++k) qb[k] = BFRAG(t3, 4 + k);
  }
  upd_keys(accB, 63, hcs, ln, u1, u2);
  #undef BFRAG

  // flush: reconstruct cols, merge best-2 across the 16 ln lanes, write part
  #pragma unroll
  for (int s = 0; s < 16; ++s) {
    uint32_t k1 = u1[s], k2 = u2[s];
    int c1 = colQ * 1024 + (int)(k1 & 63u) * 16 + ln;
    int c2 = colQ * 1024 + (int)(k2 & 63u) * 16 + ln;
    #pragma unroll
    for (int m = 1; m <= 8; m <<= 1) {
      const uint32_t o1 = (uint32_t)__shfl_xor((int)k1, m, 64);
      const int      oc1 = __shfl_xor(c1, m, 64);
      const uint32_t o2 = (uint32_t)__shfl_xor((int)k2, m, 64);
      const int      oc2 = __shfl_xor(c2, m, 64);
      const bool t1 = k1 <= o1;
      const uint32_t am = t1 ? o1 : k1; const int amc = t1 ? oc1 : c1;
      k1 = t1 ? k1 : o1;                c1 = t1 ? c1 : oc1;
      const bool t2 = k2 <= o2;
      const uint32_t bm = t2 ? k2 : o2; const int bmc = t2 ? c2 : oc2;
      const bool t3 = am <= bm;
      k2 = t3 ? am : bm;                c2 = t3 ? amc : bmc;
    }
    if (ln == 0) {
      const int rt = s >> 2, reg = s & 3;
      const int row = rg * 256 + w * 64 + rt * 16 + quad * 4 + reg;
      part[(size_t)row * 4 + colQ] = make_uint2((uint32_t)c1, (uint32_t)c2);
    }
  }
}

// ------------------------- fused fp64 rescore (8 cands) + STE update + loss
// Residual identity: res_final = x - sum(stv) exactly, so `out` is written
// only at the last layer as out = x - nr (fp diff vs ref sum order ~2e-6).
// Gather pattern dd = k*32 + dg*4: each 8-lane candidate group reads 128 B
// CONTIGUOUS per load (8 cache lines/instr instead of 64).
__global__ void post_kernel(const uint2* __restrict__ part,
                            const float* __restrict__ rsrc,  // x (q=0) or res
                            float* __restrict__ rdst,        // res
                            const float* __restrict__ xin,   // x (last layer)
                            const float* __restrict__ cb,    // layer fp32
                            float* __restrict__ out,
                            _Float16* __restrict__ At,       // row-major
                            float* __restrict__ idxf,
                            float* __restrict__ lossP,       // 256 slots
                            int writeRes, int emit, int writeOut) {
  __shared__ float ls[4];
  const int lane = threadIdx.x & 63;
  const int rsub = threadIdx.x >> 6;
  const int row = blockIdx.x * 4 + rsub;

  // lane-parallel rescore: cand id = lane>>3 (direct per-lane load, no
  // runtime-indexed local array), contiguous chunk = (lane&7)*16 B
  const int cd = lane >> 3, dg = lane & 7;
  const int myc = (int)((const uint32_t*)part)[(size_t)row * 8 + cd];
  const float* rrow = rsrc + (size_t)row * DIMD;
  const float* qrow = cb + (size_t)myc * DIMD;
  double d = 0.0;
  #pragma unroll
  for (int k = 0; k < 8; ++k) {
    const int dd = k * 32 + dg * 4;
    const float4 rv = *(const float4*)&rrow[dd];
    const float4 qv = *(const float4*)&qrow[dd];
    const double t0 = (double)rv.x - (double)qv.x;
    const double t1 = (double)rv.y - (double)qv.y;
    const double t2 = (double)rv.z - (double)qv.z;
    const double t3 = (double)rv.w - (double)qv.w;
    d += t0 * t0 + t1 * t1 + t2 * t2 + t3 * t3;
  }
  #pragma unroll
  for (int m = 1; m <= 4; m <<= 1) d += __shfl_xor(d, m, 64);
  double bd = d; int bc = myc;
  #pragma unroll
  for (int m = 8; m <= 32; m <<= 1) {
    const double od = __shfl_xor(bd, m, 64);
    const int    oc = __shfl_xor(bc, m, 64);
    if (od < bd || (od == bd && oc < bc)) { bd = od; bc = oc; }
  }
  const int win = bc;

  // STE update (reference rounding)
  const size_t base = (size_t)row * DIMD + lane * 4;
  const float4 r4 = *(const float4*)&rsrc[base];
  const float4 q4 = *(const float4*)&cb[(size_t)win * DIMD + lane * 4];
  const float rr[4] = {r4.x, r4.y, r4.z, r4.w};
  const float qq[4] = {q4.x, q4.y, q4.z, q4.w};
  float nr[4];
  float s2 = 0.f;
  #pragma unroll
  for (int j = 0; j < 4; ++j) {
    const float stv = rr[j] + (qq[j] - rr[j]);
    nr[j] = rr[j] - stv;
    const float dl = rr[j] - qq[j];
    s2 += dl * dl;
  }
  if (writeRes)
    *(float4*)&rdst[base] = make_float4(nr[0], nr[1], nr[2], nr[3]);
  if (writeOut) {
    const float4 xv = *(const float4*)&xin[base];
    *(float4*)&out[base] =
        make_float4(xv.x - nr[0], xv.y - nr[1], xv.z - nr[2], xv.w - nr[3]);
  }
  if (emit) {
    // row-major At: fully coalesced half4 store
    half4 h;
    #pragma unroll
    for (int j = 0; j < 4; ++j) h[j] = (_Float16)nr[j];
    *(half4*)&At[base] = h;
  }
  if (lane == 0) idxf[row] = (float)win;

  #pragma unroll
  for (int m = 1; m < 64; m <<= 1) s2 += __shfl_xor(s2, m, 64);
  if (lane == 0) ls[rsub] = s2;
  __syncthreads();
  if (threadIdx.x == 0) {
    const float tot = ls[0] + ls[1] + ls[2] + ls[3];
    atomicAdd(&lossP[blockIdx.x & 255],
              tot * (1.0f / (float)((size_t)NTOK * DIMD)));
  }
}

// sum 4 x 256 loss partials -> losses[4]
__global__ void finalize_kernel(const float* __restrict__ lossP,
                                float* __restrict__ losses) {
  const int w = threadIdx.x >> 6, lane = threadIdx.x & 63;
  float s = lossP[w * 256 + lane] + lossP[w * 256 + 64 + lane] +
            lossP[w * 256 + 128 + lane] + lossP[w * 256 + 192 + lane];
  #pragma unroll
  for (int m = 1; m < 64; m <<= 1) s += __shfl_xor(s, m, 64);
  if (lane == 0) losses[w] = s;
}

// ---------------------------------------------------------------- launch
extern "C" void kernel_launch(void* const* d_in, const int* in_sizes, int n_in,
                              void* d_out, int out_size, void* d_ws, size_t ws_size,
                              hipStream_t stream) {
  const float* x   = (const float*)d_in[0];   // [8,4096,256]
  const float* cbs = (const float*)d_in[1];   // [4,4096,256]

  float* out    = (float*)d_out;
  float* idxf   = out + (size_t)NTOK * DIMD;
  float* losses = idxf + (size_t)NQ * NTOK;

  char* wsp = (char*)d_ws;
  float* res = (float*)wsp;                    wsp += (size_t)NTOK * DIMD * 4;      // 32 MB
  _Float16* At = (_Float16*)wsp;               wsp += (size_t)NTOK * DIMD * 2;      // 16 MB
  _Float16* Bt = (_Float16*)wsp;               wsp += (size_t)NQ * KCB * DIMD * 2;  //  8 MB
  float* hcS = (float*)wsp;                    wsp += (size_t)NQ * KCB * 4;
  uint2* part = (uint2*)wsp;                   wsp += (size_t)NTOK * 4 * 8;
  float* lossP = (float*)wsp;                  wsp += (size_t)NQ * 256 * 4;

  hipMemsetAsync(lossP, 0, NQ * 256 * sizeof(float), stream);
  cb_prep_kernel<<<NQ * KCB / 8, 256, 0, stream>>>(cbs, Bt, hcS);
  init_kernel<<<NTOK / 8, 256, 0, stream>>>(x, At);

  for (int q = 0; q < NQ; ++q) {
    const float* cb = cbs + (size_t)q * KCB * DIMD;
    argmin_kernel<<<512, 256, 0, stream>>>(At, Bt + (size_t)q * KCB * DIMD,
                                           hcS + (size_t)q * KCB, part);
    const int last = (q == NQ - 1);
    post_kernel<<<NTOK / 4, 256, 0, stream>>>(
        part, q == 0 ? x : res, res, x, cb, out, At,
        idxf + (size_t)q * NTOK, lossP + (size_t)q * 256,
        /*writeRes=*/!last, /*emit=*/!last, /*writeOut=*/last);
  }
  finalize_kernel<<<1, 256, 0, stream>>>(lossP, losses);
}

// Round 8
// 542.887 us; speedup vs baseline: 2.0985x; 2.0985x over previous
//
#include <hip/hip_runtime.h>
#include <cstdint>

#define DIMD 256
#define KCB  4096
#define NQ   4
#define NTOK 32768   // 8 * 4096

typedef __attribute__((ext_vector_type(8))) _Float16 half8;
typedef __attribute__((ext_vector_type(4))) _Float16 half4;
typedef __attribute__((ext_vector_type(4))) float f32x4;

// ---------------------------------------------------------------- helpers
__device__ __forceinline__ f32x4 mfma16(half8 a, half8 b, f32x4 c) {
  return __builtin_amdgcn_mfma_f32_16x16x32_f16(a, b, c, 0, 0, 0);
}

// ---------------------------------------------------------------- prep
// At is ROW-MAJOR fp16 [NTOK][256]: init and post's emit are fully
// coalesced; argmin does the MFMA fragment gather on its once-per-kernel
// A-load (amortized over 64 tiles).
__global__ void init_kernel(const float* __restrict__ x,
                            _Float16* __restrict__ At) {
  const int tid = threadIdx.x;
  const int n = blockIdx.x * 8 + (tid >> 5);
  const int t = tid & 31;
  const size_t base = (size_t)n * DIMD + t * 8;
  const float4 v0 = *(const float4*)&x[base];
  const float4 v1 = *(const float4*)&x[base + 4];
  const float f[8] = {v0.x, v0.y, v0.z, v0.w, v1.x, v1.y, v1.z, v1.w};
  half8 h;
  #pragma unroll
  for (int j = 0; j < 8; ++j) h[j] = (_Float16)f[j];
  *(half8*)&At[base] = h;
}

// B plane frag-linear, 64-col-chunk-major (one 64-col chunk = contiguous 32 KB):
// frag f = ((c>>6)*8 + kc)*4 + ((c>>4)&3); half = (f*64 + q*16 + (c&15))*8 + j.
// hcS[c] = 512 + 0.5*|cb_c|^2  (argmin key offset; d' = hcS - dot > 0 always).
__global__ void cb_prep_kernel(const float* __restrict__ cbs,
                               _Float16* __restrict__ Bt,
                               float* __restrict__ hcS) {
  const int tid = threadIdx.x;
  const int R = blockIdx.x * 8 + (tid >> 5);   // layer*4096 + code
  const int layer = R >> 12, c = R & 4095;
  const int t = tid & 31;
  const size_t base = (size_t)R * DIMD + t * 8;
  const float4 v0 = *(const float4*)&cbs[base];
  const float4 v1 = *(const float4*)&cbs[base + 4];
  const float f[8] = {v0.x, v0.y, v0.z, v0.w, v1.x, v1.y, v1.z, v1.w};
  half8 h;
  float s = 0.f;
  #pragma unroll
  for (int j = 0; j < 8; ++j) { h[j] = (_Float16)f[j]; s += f[j] * f[j]; }
  const int kc = t >> 2, q = t & 3;
  _Float16* BtL = Bt + (size_t)layer * KCB * DIMD;
  const int fr = ((c >> 6) * 8 + kc) * 4 + ((c >> 4) & 3);
  *(half8*)&BtL[((size_t)fr * 64 + q * 16 + (c & 15)) * 8] = h;
  #pragma unroll
  for (int off = 16; off > 0; off >>= 1) s += __shfl_down(s, off, 32);
  if (t == 0) hcS[R] = 512.0f + 0.5f * s;
}

// ---------------------------------------------------------------- argmin
// A resident in registers (64 rows x 256 d per wave); B streamed directly
// from L2. Register-budgeted pipeline (2 waves/SIMD -> 256 unified regs/wave;
// round-7 lesson: 272 spills catastrophically):
//   a[4][8]=128 (AGPR) + pa/pb/qa=48 + acc=16 (single, keys inline)
//   + u1/u2=32 + hv prefetch 2 + misc ~12  ->  ~238.
// p-leg depth-2 (refill 2 tiles ahead, ~2500 cyc cover); q-leg depth-1
// (~600 cyc cover); hcs value for the NEXT tile prefetched into hv so keys
// never wait on the ds_read. No barriers in the main loop.
__device__ __forceinline__ void upd_keys(const f32x4 (&acc)[4], int tl,
                                         float hcv,
                                         uint32_t* __restrict__ u1,
                                         uint32_t* __restrict__ u2) {
  #pragma unroll
  for (int rt = 0; rt < 4; ++rt)
    #pragma unroll
    for (int reg = 0; reg < 4; ++reg) {
      const uint32_t k =
          (__float_as_uint(hcv - acc[rt][reg]) & 0xFFFFFFC0u) | (uint32_t)tl;
      const int s = rt * 4 + reg;
      const uint32_t mx = u1[s] > k ? u1[s] : k;
      u1[s] = u1[s] < k ? u1[s] : k;
      u2[s] = u2[s] < mx ? u2[s] : mx;
    }
}

// 16 MFMAs consuming one half-tile buffer (kc0 = 0 or 4); INIT zero-inits acc.
template <bool INIT>
__device__ __forceinline__ void half_mfma(f32x4 (&acc)[4],
                                          const half8 (&a)[4][8],
                                          const half8 (&b)[4], int kc0) {
  __builtin_amdgcn_s_setprio(1);
  if constexpr (INIT) {
    const f32x4 z = {0.f, 0.f, 0.f, 0.f};
    acc[0] = mfma16(a[0][kc0], b[0], z);
    acc[1] = mfma16(a[1][kc0], b[0], z);
    acc[2] = mfma16(a[2][kc0], b[0], z);
    acc[3] = mfma16(a[3][kc0], b[0], z);
  } else {
    #pragma unroll
    for (int rt = 0; rt < 4; ++rt)
      acc[rt] = mfma16(a[rt][kc0], b[0], acc[rt]);
  }
  #pragma unroll
  for (int kc = 1; kc < 4; ++kc)
    #pragma unroll
    for (int rt = 0; rt < 4; ++rt)
      acc[rt] = mfma16(a[rt][kc0 + kc], b[kc], acc[rt]);
  __builtin_amdgcn_s_setprio(0);
}

__global__ __launch_bounds__(256, 2) void argmin_kernel(
    const _Float16* __restrict__ At,     // row-major [NTOK][256]
    const _Float16* __restrict__ Bt,     // layer base (chunk-major frag-linear)
    const float* __restrict__ hcS,       // layer base
    uint2* __restrict__ part)            // [NTOK][4] best-2 col indices
{
  __shared__ float hcs[1024];

  const int tid = threadIdx.x;
  const int lane = tid & 63, w = tid >> 6;   // 4 waves
  const int rg   = blockIdx.x & 127;         // stride-128 siblings share rows
  const int colQ = blockIdx.x >> 7;
  const int quad = lane >> 4, ln = lane & 15;

  // stage hcS quarter to LDS (1024 floats)
  *(float4*)&hcs[tid * 4] = *(const float4*)&hcS[colQ * 1024 + tid * 4];

  // upfront A fragment gather from row-major At:
  // a[rt][kc][j] = A[rb16+rt tile, row ln][kc*32 + quad*8 + j]
  const int rb16 = rg * 16 + w * 4;
  half8 a[4][8];
  #pragma unroll
  for (int kc = 0; kc < 8; ++kc)
    #pragma unroll
    for (int rt = 0; rt < 4; ++rt)
      a[rt][kc] = *(const half8*)&At[((size_t)(rb16 + rt) * 16 + ln) * DIMD +
                                     kc * 32 + quad * 8];

  // best-2 keys per element (16 rows/lane): key = trunc6(as_uint(d')) | tile
  uint32_t u1[16], u2[16];
  #pragma unroll
  for (int s = 0; s < 16; ++s) { u1[s] = 0xFFFFFFFFu; u2[s] = 0xFFFFFFFFu; }

  // quarter base: colQ*1024 cols * 256 d = colQ * 262144 halves
  const _Float16* Bq = Bt + (size_t)colQ * 262144 + lane * 8;
  // frag address for (tile t, kc): ((t>>2)*8 + kc)*4 + (t&3), 512 halves each
  #define BFRAG(t, kc) \
    (*(const half8*)&Bq[(size_t)((((t) >> 2) * 8 + (kc)) * 4 + ((t) & 3)) * 512])

  half8 pa[4], qa[4], pb[4];
  #pragma unroll
  for (int k = 0; k < 4; ++k) pa[k] = BFRAG(0, k);
  #pragma unroll
  for (int k = 0; k < 4; ++k) qa[k] = BFRAG(0, 4 + k);
  #pragma unroll
  for (int k = 0; k < 4; ++k) pb[k] = BFRAG(1, k);

  __syncthreads();   // hcs ready (only barrier in the kernel)

  float hv = hcs[ln];   // hcs value for tile 0 (prefetched)
  f32x4 acc[4];

  // 2-tile body, no peel: loop covers tiles 0..63; wrap mask keeps the
  // final dead refills in-bounds.
  for (int t = 0; t < 64; t += 2) {
    const int t1 = (t + 1) & 63, t2 = (t + 2) & 63, t3 = (t + 3) & 63;
    // ---- tile t (even): P = pa (issued 2 tiles ago)
    half_mfma<true >(acc, a, pa, 0);
    #pragma unroll
    for (int k = 0; k < 4; ++k) pa[k] = BFRAG(t2, k);       // depth-2 refill
    half_mfma<false>(acc, a, qa, 4);
    #pragma unroll
    for (int k = 0; k < 4; ++k) qa[k] = BFRAG(t1, 4 + k);   // q for tile t+1
    float hvn = hcs[t1 * 16 + ln];                          // prefetch keys src
    upd_keys(acc, t, hv, u1, u2);
    hv = hvn;
    // ---- tile t+1 (odd): P = pb (issued 2 tiles ago)
    half_mfma<true >(acc, a, pb, 0);
    #pragma unroll
    for (int k = 0; k < 4; ++k) pb[k] = BFRAG(t3, k);       // depth-2 refill
    half_mfma<false>(acc, a, qa, 4);
    #pragma unroll
    for (int k = 0; k < 4; ++k) qa[k] = BFRAG(t2, 4 + k);   // q for tile t+2
    hvn = hcs[t2 * 16 + ln];
    upd_keys(acc, t + 1, hv, u1, u2);
    hv = hvn;
  }
  #undef BFRAG

  // flush: reconstruct cols, merge best-2 across the 16 ln lanes, write part
  #pragma unroll
  for (int s = 0; s < 16; ++s) {
    uint32_t k1 = u1[s], k2 = u2[s];
    int c1 = colQ * 1024 + (int)(k1 & 63u) * 16 + ln;
    int c2 = colQ * 1024 + (int)(k2 & 63u) * 16 + ln;
    #pragma unroll
    for (int m = 1; m <= 8; m <<= 1) {
      const uint32_t o1 = (uint32_t)__shfl_xor((int)k1, m, 64);
      const int      oc1 = __shfl_xor(c1, m, 64);
      const uint32_t o2 = (uint32_t)__shfl_xor((int)k2, m, 64);
      const int      oc2 = __shfl_xor(c2, m, 64);
      const bool t1 = k1 <= o1;
      const uint32_t am = t1 ? o1 : k1; const int amc = t1 ? oc1 : c1;
      k1 = t1 ? k1 : o1;                c1 = t1 ? c1 : oc1;
      const bool t2 = k2 <= o2;
      const uint32_t bm = t2 ? k2 : o2; const int bmc = t2 ? c2 : oc2;
      const bool t3 = am <= bm;
      k2 = t3 ? am : bm;                c2 = t3 ? amc : bmc;
    }
    if (ln == 0) {
      const int rt = s >> 2, reg = s & 3;
      const int row = rg * 256 + w * 64 + rt * 16 + quad * 4 + reg;
      part[(size_t)row * 4 + colQ] = make_uint2((uint32_t)c1, (uint32_t)c2);
    }
  }
}

// ------------------------- fused fp64 rescore (8 cands) + STE update + loss
// Residual identity: res_final = x - sum(stv) exactly, so `out` is written
// only at the last layer as out = x - nr (fp diff vs ref sum order ~2e-6).
// Gather pattern dd = k*32 + dg*4: each 8-lane candidate group reads 128 B
// CONTIGUOUS per load (8 cache lines/instr instead of 64).
__global__ void post_kernel(const uint2* __restrict__ part,
                            const float* __restrict__ rsrc,  // x (q=0) or res
                            float* __restrict__ rdst,        // res
                            const float* __restrict__ xin,   // x (last layer)
                            const float* __restrict__ cb,    // layer fp32
                            float* __restrict__ out,
                            _Float16* __restrict__ At,       // row-major
                            float* __restrict__ idxf,
                            float* __restrict__ lossP,       // 256 slots
                            int writeRes, int emit, int writeOut) {
  __shared__ float ls[4];
  const int lane = threadIdx.x & 63;
  const int rsub = threadIdx.x >> 6;
  const int row = blockIdx.x * 4 + rsub;

  // lane-parallel rescore: cand id = lane>>3 (direct per-lane load, no
  // runtime-indexed local array), contiguous chunk = (lane&7)*16 B
  const int cd = lane >> 3, dg = lane & 7;
  const int myc = (int)((const uint32_t*)part)[(size_t)row * 8 + cd];
  const float* rrow = rsrc + (size_t)row * DIMD;
  const float* qrow = cb + (size_t)myc * DIMD;
  double d = 0.0;
  #pragma unroll
  for (int k = 0; k < 8; ++k) {
    const int dd = k * 32 + dg * 4;
    const float4 rv = *(const float4*)&rrow[dd];
    const float4 qv = *(const float4*)&qrow[dd];
    const double t0 = (double)rv.x - (double)qv.x;
    const double t1 = (double)rv.y - (double)qv.y;
    const double t2 = (double)rv.z - (double)qv.z;
    const double t3 = (double)rv.w - (double)qv.w;
    d += t0 * t0 + t1 * t1 + t2 * t2 + t3 * t3;
  }
  #pragma unroll
  for (int m = 1; m <= 4; m <<= 1) d += __shfl_xor(d, m, 64);
  double bd = d; int bc = myc;
  #pragma unroll
  for (int m = 8; m <= 32; m <<= 1) {
    const double od = __shfl_xor(bd, m, 64);
    const int    oc = __shfl_xor(bc, m, 64);
    if (od < bd || (od == bd && oc < bc)) { bd = od; bc = oc; }
  }
  const int win = bc;

  // STE update (reference rounding)
  const size_t base = (size_t)row * DIMD + lane * 4;
  const float4 r4 = *(const float4*)&rsrc[base];
  const float4 q4 = *(const float4*)&cb[(size_t)win * DIMD + lane * 4];
  const float rr[4] = {r4.x, r4.y, r4.z, r4.w};
  const float qq[4] = {q4.x, q4.y, q4.z, q4.w};
  float nr[4];
  float s2 = 0.f;
  #pragma unroll
  for (int j = 0; j < 4; ++j) {
    const float stv = rr[j] + (qq[j] - rr[j]);
    nr[j] = rr[j] - stv;
    const float dl = rr[j] - qq[j];
    s2 += dl * dl;
  }
  if (writeRes)
    *(float4*)&rdst[base] = make_float4(nr[0], nr[1], nr[2], nr[3]);
  if (writeOut) {
    const float4 xv = *(const float4*)&xin[base];
    *(float4*)&out[base] =
        make_float4(xv.x - nr[0], xv.y - nr[1], xv.z - nr[2], xv.w - nr[3]);
  }
  if (emit) {
    // row-major At: fully coalesced half4 store
    half4 h;
    #pragma unroll
    for (int j = 0; j < 4; ++j) h[j] = (_Float16)nr[j];
    *(half4*)&At[base] = h;
  }
  if (lane == 0) idxf[row] = (float)win;

  #pragma unroll
  for (int m = 1; m < 64; m <<= 1) s2 += __shfl_xor(s2, m, 64);
  if (lane == 0) ls[rsub] = s2;
  __syncthreads();
  if (threadIdx.x == 0) {
    const float tot = ls[0] + ls[1] + ls[2] + ls[3];
    atomicAdd(&lossP[blockIdx.x & 255],
              tot * (1.0f / (float)((size_t)NTOK * DIMD)));
  }
}

// sum 4 x 256 loss partials -> losses[4]
__global__ void finalize_kernel(const float* __restrict__ lossP,
                                float* __restrict__ losses) {
  const int w = threadIdx.x >> 6, lane = threadIdx.x & 63;
  float s = lossP[w * 256 + lane] + lossP[w * 256 + 64 + lane] +
            lossP[w * 256 + 128 + lane] + lossP[w * 256 + 192 + lane];
  #pragma unroll
  for (int m = 1; m < 64; m <<= 1) s += __shfl_xor(s, m, 64);
  if (lane == 0) losses[w] = s;
}

// ---------------------------------------------------------------- launch
extern "C" void kernel_launch(void* const* d_in, const int* in_sizes, int n_in,
                              void* d_out, int out_size, void* d_ws, size_t ws_size,
                              hipStream_t stream) {
  const float* x   = (const float*)d_in[0];   // [8,4096,256]
  const float* cbs = (const float*)d_in[1];   // [4,4096,256]

  float* out    = (float*)d_out;
  float* idxf   = out + (size_t)NTOK * DIMD;
  float* losses = idxf + (size_t)NQ * NTOK;

  char* wsp = (char*)d_ws;
  float* res = (float*)wsp;                    wsp += (size_t)NTOK * DIMD * 4;      // 32 MB
  _Float16* At = (_Float16*)wsp;               wsp += (size_t)NTOK * DIMD * 2;      // 16 MB
  _Float16* Bt = (_Float16*)wsp;               wsp += (size_t)NQ * KCB * DIMD * 2;  //  8 MB
  float* hcS = (float*)wsp;                    wsp += (size_t)NQ * KCB * 4;
  uint2* part = (uint2*)wsp;                   wsp += (size_t)NTOK * 4 * 8;
  float* lossP = (float*)wsp;                  wsp += (size_t)NQ * 256 * 4;

  hipMemsetAsync(lossP, 0, NQ * 256 * sizeof(float), stream);
  cb_prep_kernel<<<NQ * KCB / 8, 256, 0, stream>>>(cbs, Bt, hcS);
  init_kernel<<<NTOK / 8, 256, 0, stream>>>(x, At);

  for (int q = 0; q < NQ; ++q) {
    const float* cb = cbs + (size_t)q * KCB * DIMD;
    argmin_kernel<<<512, 256, 0, stream>>>(At, Bt + (size_t)q * KCB * DIMD,
                                           hcS + (size_t)q * KCB, part);
    const int last = (q == NQ - 1);
    post_kernel<<<NTOK / 4, 256, 0, stream>>>(
        part, q == 0 ? x : res, res, x, cb, out, At,
        idxf + (size_t)q * NTOK, lossP + (size_t)q * 256,
        /*writeRes=*/!last, /*emit=*/!last, /*writeOut=*/last);
  }
  finalize_kernel<<<1, 256, 0, stream>>>(lossP, losses);
}

// Round 9
// 530.158 us; speedup vs baseline: 2.1489x; 1.0240x over previous
//
#include <hip/hip_runtime.h>
#include <cstdint>

#define DIMD 256
#define KCB  4096
#define NQ   4
#define NTOK 32768   // 8 * 4096

typedef __attribute__((ext_vector_type(8))) _Float16 half8;
typedef __attribute__((ext_vector_type(4))) _Float16 half4;
typedef __attribute__((ext_vector_type(4))) float f32x4;

#define VMCNT(n) asm volatile("s_waitcnt vmcnt(" #n ")" ::: "memory")

// ---------------------------------------------------------------- helpers
__device__ __forceinline__ void async16(const void* g, void* l) {
  __builtin_amdgcn_global_load_lds(
      (const __attribute__((address_space(1))) unsigned int*)g,
      (__attribute__((address_space(3))) unsigned int*)l, 16, 0, 0);
}

__device__ __forceinline__ f32x4 mfma16(half8 a, half8 b, f32x4 c) {
  return __builtin_amdgcn_mfma_f32_16x16x32_f16(a, b, c, 0, 0, 0);
}

// ---------------------------------------------------------------- prep
// At is ROW-MAJOR fp16 [NTOK][256]: init and post's emit are fully
// coalesced; argmin does the MFMA fragment gather on its once-per-kernel
// A-load (amortized over 64 tiles).
__global__ void init_kernel(const float* __restrict__ x,
                            _Float16* __restrict__ At) {
  const int tid = threadIdx.x;
  const int n = blockIdx.x * 8 + (tid >> 5);
  const int t = tid & 31;
  const size_t base = (size_t)n * DIMD + t * 8;
  const float4 v0 = *(const float4*)&x[base];
  const float4 v1 = *(const float4*)&x[base + 4];
  const float f[8] = {v0.x, v0.y, v0.z, v0.w, v1.x, v1.y, v1.z, v1.w};
  half8 h;
  #pragma unroll
  for (int j = 0; j < 8; ++j) h[j] = (_Float16)f[j];
  *(half8*)&At[base] = h;
}

// B plane frag-linear, 64-col-chunk-major (one 64-col chunk = contiguous 32 KB):
// frag f = ((c>>6)*8 + kc)*4 + ((c>>4)&3); half = (f*64 + q*16 + (c&15))*8 + j.
// hcS[c] = 512 + 0.5*|cb_c|^2  (argmin key offset; d' = hcS - dot > 0 always).
__global__ void cb_prep_kernel(const float* __restrict__ cbs,
                               _Float16* __restrict__ Bt,
                               float* __restrict__ hcS) {
  const int tid = threadIdx.x;
  const int R = blockIdx.x * 8 + (tid >> 5);   // layer*4096 + code
  const int layer = R >> 12, c = R & 4095;
  const int t = tid & 31;
  const size_t base = (size_t)R * DIMD + t * 8;
  const float4 v0 = *(const float4*)&cbs[base];
  const float4 v1 = *(const float4*)&cbs[base + 4];
  const float f[8] = {v0.x, v0.y, v0.z, v0.w, v1.x, v1.y, v1.z, v1.w};
  half8 h;
  float s = 0.f;
  #pragma unroll
  for (int j = 0; j < 8; ++j) { h[j] = (_Float16)f[j]; s += f[j] * f[j]; }
  const int kc = t >> 2, q = t & 3;
  _Float16* BtL = Bt + (size_t)layer * KCB * DIMD;
  const int fr = ((c >> 6) * 8 + kc) * 4 + ((c >> 4) & 3);
  *(half8*)&BtL[((size_t)fr * 64 + q * 16 + (c & 15)) * 8] = h;
  #pragma unroll
  for (int off = 16; off > 0; off >>= 1) s += __shfl_down(s, off, 32);
  if (t == 0) hcS[R] = 512.0f + 0.5f * s;
}

// ---------------------------------------------------------------- argmin
// A resident in registers; B pipelined through WAVE-PRIVATE LDS rings:
// each wave stages its own 4 KB half-tiles via global_load_lds into a
// 4-slot ring (16 KB/wave), depth 3 half-phases (~1200 cyc cover), with
// per-wave counted VMCNT(4) -- exact because the only vmem in flight after
// the one __syncthreads is this wave's own async16 stream. No barriers in
// the main loop, no block-wide phase locking, and pipeline depth costs LDS
// (idle anyway) instead of VGPRs (the resource that killed rounds 7/8).
// Ledger @2 waves/SIMD (256 regs): a=128(AGPR) + bA/bB=32 + acc=16 + u=32
// + misc ~20 = ~228.
__device__ __forceinline__ void upd_keys(const f32x4 (&acc)[4], int tl,
                                         const float* __restrict__ hcs, int ln,
                                         uint32_t* __restrict__ u1,
                                         uint32_t* __restrict__ u2) {
  const float hcv = hcs[tl * 16 + ln];
  #pragma unroll
  for (int rt = 0; rt < 4; ++rt)
    #pragma unroll
    for (int reg = 0; reg < 4; ++reg) {
      const uint32_t k =
          (__float_as_uint(hcv - acc[rt][reg]) & 0xFFFFFFC0u) | (uint32_t)tl;
      const int s = rt * 4 + reg;
      const uint32_t mx = u1[s] > k ? u1[s] : k;
      u1[s] = u1[s] < k ? u1[s] : k;
      u2[s] = u2[s] < mx ? u2[s] : mx;
    }
}

// 16 MFMAs consuming one half-tile buffer (kc0 = 0 or 4); INIT zero-inits acc.
template <bool INIT>
__device__ __forceinline__ void half_mfma(f32x4 (&acc)[4],
                                          const half8 (&a)[4][8],
                                          const half8 (&b)[4], int kc0) {
  __builtin_amdgcn_s_setprio(1);
  if constexpr (INIT) {
    const f32x4 z = {0.f, 0.f, 0.f, 0.f};
    acc[0] = mfma16(a[0][kc0], b[0], z);
    acc[1] = mfma16(a[1][kc0], b[0], z);
    acc[2] = mfma16(a[2][kc0], b[0], z);
    acc[3] = mfma16(a[3][kc0], b[0], z);
  } else {
    #pragma unroll
    for (int rt = 0; rt < 4; ++rt)
      acc[rt] = mfma16(a[rt][kc0], b[0], acc[rt]);
  }
  #pragma unroll
  for (int kc = 1; kc < 4; ++kc)
    #pragma unroll
    for (int rt = 0; rt < 4; ++rt)
      acc[rt] = mfma16(a[rt][kc0 + kc], b[kc], acc[rt]);
  __builtin_amdgcn_s_setprio(0);
}

// stage half-phase k: tile t=(k>>1)&63, half hf=k&1, frags kc=hf*4+r,
// dest = this wave's ring slot (k&3). Global src is per-lane (Bq includes
// lane*16); LDS dest is wave-uniform + HW lane*16.
__device__ __forceinline__ void stage_half(const char* __restrict__ Bq,
                                           _Float16* __restrict__ myL, int k) {
  const int t = (k >> 1) & 63, hf = k & 1, sl = k & 3;
  #pragma unroll
  for (int r = 0; r < 4; ++r)
    async16(Bq + (size_t)((((t >> 2) * 8 + (hf * 4 + r)) * 4 + (t & 3)) * 1024),
            (char*)myL + sl * 4096 + r * 1024);
}

__device__ __forceinline__ void ldb(half8 (&b)[4],
                                    const _Float16* __restrict__ myL,
                                    int sl, int lane) {
  #pragma unroll
  for (int k = 0; k < 4; ++k)
    b[k] = *(const half8*)&myL[sl * 2048 + k * 512 + lane * 8];
}

__global__ __launch_bounds__(256, 2) void argmin_kernel(
    const _Float16* __restrict__ At,     // row-major [NTOK][256]
    const _Float16* __restrict__ Bt,     // layer base (chunk-major frag-linear)
    const float* __restrict__ hcS,       // layer base
    uint2* __restrict__ part)            // [NTOK][4] best-2 col indices
{
  __shared__ _Float16 Bls[4][8192];      // 4 waves x (4 slots x 4 KB) = 64 KB
  __shared__ float hcs[1024];

  const int tid = threadIdx.x;
  const int lane = tid & 63, w = tid >> 6;   // 4 waves
  const int rg   = blockIdx.x & 127;         // stride-128 siblings share rows
  const int colQ = blockIdx.x >> 7;
  const int quad = lane >> 4, ln = lane & 15;

  // stage hcS quarter to LDS (1024 floats)
  *(float4*)&hcs[tid * 4] = *(const float4*)&hcS[colQ * 1024 + tid * 4];

  // upfront A fragment gather from row-major At:
  // a[rt][kc][j] = A[rb16+rt tile, row ln][kc*32 + quad*8 + j]
  const int rb16 = rg * 16 + w * 4;
  half8 a[4][8];
  #pragma unroll
  for (int kc = 0; kc < 8; ++kc)
    #pragma unroll
    for (int rt = 0; rt < 4; ++rt)
      a[rt][kc] = *(const half8*)&At[((size_t)(rb16 + rt) * 16 + ln) * DIMD +
                                     kc * 32 + quad * 8];

  // best-2 keys per element (16 rows/lane): key = trunc6(as_uint(d')) | tile
  uint32_t u1[16], u2[16];
  #pragma unroll
  for (int s = 0; s < 16; ++s) { u1[s] = 0xFFFFFFFFu; u2[s] = 0xFFFFFFFFu; }

  // per-lane global base of this block's B quarter
  const char* Bq = (const char*)(Bt + (size_t)colQ * 262144) + lane * 16;
  _Float16* myL = &Bls[w][0];   // wave-private 16 KB ring

  // Drain everything (A gather, hcs): compiler emits full vmcnt(0) before
  // the barrier, so from here on the ONLY vmem in flight is our async16
  // stream and the VMCNT counts below are exact.
  __syncthreads();

  // prologue: stage half-phases 0,1,2 (depth 3)
  stage_half(Bq, myL, 0);
  stage_half(Bq, myL, 1);
  stage_half(Bq, myL, 2);
  VMCNT(8);                      // phase-0 loads retired
  half8 bA[4], bB[4];
  ldb(bA, myL, 0, lane);         // b(0): tile 0 half 0

  f32x4 acc[4];

  // 4 half-phases per iteration (tiles 2u, 2u+1); slot indices static.
  // Invariant entering P0: outstanding = stages {4u+1, 4u+2}; bA = b(4u).
  for (int u = 0; u < 32; ++u) {
    const int t0 = 2 * u, t1 = 2 * u + 1;
    // P0: consume bA (tile t0, kc 0..3)
    VMCNT(4);                    // stage(4u+1) retired
    ldb(bB, myL, 1, lane);       // b(4u+1): tile t0 half 1
    stage_half(Bq, myL, 4 * u + 3);
    half_mfma<true >(acc, a, bA, 0);
    // P1: consume bB (tile t0, kc 4..7)
    VMCNT(4);                    // stage(4u+2) retired
    ldb(bA, myL, 2, lane);       // b(4u+2): tile t1 half 0
    stage_half(Bq, myL, 4 * u + 4);
    half_mfma<false>(acc, a, bB, 4);
    upd_keys(acc, t0, hcs, ln, u1, u2);
    // P2: consume bA (tile t1, kc 0..3)
    VMCNT(4);                    // stage(4u+3) retired
    ldb(bB, myL, 3, lane);       // b(4u+3): tile t1 half 1
    stage_half(Bq, myL, 4 * u + 5);
    half_mfma<true >(acc, a, bA, 0);
    // P3: consume bB (tile t1, kc 4..7)
    VMCNT(4);                    // stage(4u+4) retired
    ldb(bA, myL, 0, lane);       // b(4u+4): tile t1+1 half 0 (wraps at end)
    stage_half(Bq, myL, 4 * u + 6);
    half_mfma<false>(acc, a, bB, 4);
    upd_keys(acc, t1, hcs, ln, u1, u2);
  }

  // flush: reconstruct cols, merge best-2 across the 16 ln lanes, write part
  #pragma unroll
  for (int s = 0; s < 16; ++s) {
    uint32_t k1 = u1[s], k2 = u2[s];
    int c1 = colQ * 1024 + (int)(k1 & 63u) * 16 + ln;
    int c2 = colQ * 1024 + (int)(k2 & 63u) * 16 + ln;
    #pragma unroll
    for (int m = 1; m <= 8; m <<= 1) {
      const uint32_t o1 = (uint32_t)__shfl_xor((int)k1, m, 64);
      const int      oc1 = __shfl_xor(c1, m, 64);
      const uint32_t o2 = (uint32_t)__shfl_xor((int)k2, m, 64);
      const int      oc2 = __shfl_xor(c2, m, 64);
      const bool t1 = k1 <= o1;
      const uint32_t am = t1 ? o1 : k1; const int amc = t1 ? oc1 : c1;
      k1 = t1 ? k1 : o1;                c1 = t1 ? c1 : oc1;
      const bool t2 = k2 <= o2;
      const uint32_t bm = t2 ? k2 : o2; const int bmc = t2 ? c2 : oc2;
      const bool t3 = am <= bm;
      k2 = t3 ? am : bm;                c2 = t3 ? amc : bmc;
    }
    if (ln == 0) {
      const int rt = s >> 2, reg = s & 3;
      const int row = rg * 256 + w * 64 + rt * 16 + quad * 4 + reg;
      part[(size_t)row * 4 + colQ] = make_uint2((uint32_t)c1, (uint32_t)c2);
    }
  }
}

// ------------------------- fused fp64 rescore (8 cands) + STE update + loss
// Residual identity: res_final = x - sum(stv) exactly, so `out` is written
// only at the last layer as out = x - nr (fp diff vs ref sum order ~2e-6).
// Gather pattern dd = k*32 + dg*4: each 8-lane candidate group reads 128 B
// CONTIGUOUS per load (8 cache lines/instr instead of 64).
__global__ void post_kernel(const uint2* __restrict__ part,
                            const float* __restrict__ rsrc,  // x (q=0) or res
                            float* __restrict__ rdst,        // res
                            const float* __restrict__ xin,   // x (last layer)
                            const float* __restrict__ cb,    // layer fp32
                            float* __restrict__ out,
                            _Float16* __restrict__ At,       // row-major
                            float* __restrict__ idxf,
                            float* __restrict__ lossP,       // 256 slots
                            int writeRes, int emit, int writeOut) {
  __shared__ float ls[4];
  const int lane = threadIdx.x & 63;
  const int rsub = threadIdx.x >> 6;
  const int row = blockIdx.x * 4 + rsub;

  // lane-parallel rescore: cand id = lane>>3 (direct per-lane load, no
  // runtime-indexed local array), contiguous chunk = (lane&7)*16 B
  const int cd = lane >> 3, dg = lane & 7;
  const int myc = (int)((const uint32_t*)part)[(size_t)row * 8 + cd];
  const float* rrow = rsrc + (size_t)row * DIMD;
  const float* qrow = cb + (size_t)myc * DIMD;
  double d = 0.0;
  #pragma unroll
  for (int k = 0; k < 8; ++k) {
    const int dd = k * 32 + dg * 4;
    const float4 rv = *(const float4*)&rrow[dd];
    const float4 qv = *(const float4*)&qrow[dd];
    const double t0 = (double)rv.x - (double)qv.x;
    const double t1 = (double)rv.y - (double)qv.y;
    const double t2 = (double)rv.z - (double)qv.z;
    const double t3 = (double)rv.w - (double)qv.w;
    d += t0 * t0 + t1 * t1 + t2 * t2 + t3 * t3;
  }
  #pragma unroll
  for (int m = 1; m <= 4; m <<= 1) d += __shfl_xor(d, m, 64);
  double bd = d; int bc = myc;
  #pragma unroll
  for (int m = 8; m <= 32; m <<= 1) {
    const double od = __shfl_xor(bd, m, 64);
    const int    oc = __shfl_xor(bc, m, 64);
    if (od < bd || (od == bd && oc < bc)) { bd = od; bc = oc; }
  }
  const int win = bc;

  // STE update (reference rounding)
  const size_t base = (size_t)row * DIMD + lane * 4;
  const float4 r4 = *(const float4*)&rsrc[base];
  const float4 q4 = *(const float4*)&cb[(size_t)win * DIMD + lane * 4];
  const float rr[4] = {r4.x, r4.y, r4.z, r4.w};
  const float qq[4] = {q4.x, q4.y, q4.z, q4.w};
  float nr[4];
  float s2 = 0.f;
  #pragma unroll
  for (int j = 0; j < 4; ++j) {
    const float stv = rr[j] + (qq[j] - rr[j]);
    nr[j] = rr[j] - stv;
    const float dl = rr[j] - qq[j];
    s2 += dl * dl;
  }
  if (writeRes)
    *(float4*)&rdst[base] = make_float4(nr[0], nr[1], nr[2], nr[3]);
  if (writeOut) {
    const float4 xv = *(const float4*)&xin[base];
    *(float4*)&out[base] =
        make_float4(xv.x - nr[0], xv.y - nr[1], xv.z - nr[2], xv.w - nr[3]);
  }
  if (emit) {
    // row-major At: fully coalesced half4 store
    half4 h;
    #pragma unroll
    for (int j = 0; j < 4; ++j) h[j] = (_Float16)nr[j];
    *(half4*)&At[base] = h;
  }
  if (lane == 0) idxf[row] = (float)win;

  #pragma unroll
  for (int m = 1; m < 64; m <<= 1) s2 += __shfl_xor(s2, m, 64);
  if (lane == 0) ls[rsub] = s2;
  __syncthreads();
  if (threadIdx.x == 0) {
    const float tot = ls[0] + ls[1] + ls[2] + ls[3];
    atomicAdd(&lossP[blockIdx.x & 255],
              tot * (1.0f / (float)((size_t)NTOK * DIMD)));
  }
}

// sum 4 x 256 loss partials -> losses[4]
__global__ void finalize_kernel(const float* __restrict__ lossP,
                                float* __restrict__ losses) {
  const int w = threadIdx.x >> 6, lane = threadIdx.x & 63;
  float s = lossP[w * 256 + lane] + lossP[w * 256 + 64 + lane] +
            lossP[w * 256 + 128 + lane] + lossP[w * 256 + 192 + lane];
  #pragma unroll
  for (int m = 1; m < 64; m <<= 1) s += __shfl_xor(s, m, 64);
  if (lane == 0) losses[w] = s;
}

// ---------------------------------------------------------------- launch
extern "C" void kernel_launch(void* const* d_in, const int* in_sizes, int n_in,
                              void* d_out, int out_size, void* d_ws, size_t ws_size,
                              hipStream_t stream) {
  const float* x   = (const float*)d_in[0];   // [8,4096,256]
  const float* cbs = (const float*)d_in[1];   // [4,4096,256]

  float* out    = (float*)d_out;
  float* idxf   = out + (size_t)NTOK * DIMD;
  float* losses = idxf + (size_t)NQ * NTOK;

  char* wsp = (char*)d_ws;
  float* res = (float*)wsp;                    wsp += (size_t)NTOK * DIMD * 4;      // 32 MB
  _Float16* At = (_Float16*)wsp;               wsp += (size_t)NTOK * DIMD * 2;      // 16 MB
  _Float16* Bt = (_Float16*)wsp;               wsp += (size_t)NQ * KCB * DIMD * 2;  //  8 MB
  float* hcS = (float*)wsp;                    wsp += (size_t)NQ * KCB * 4;
  uint2* part = (uint2*)wsp;                   wsp += (size_t)NTOK * 4 * 8;
  float* lossP = (float*)wsp;                  wsp += (size_t)NQ * 256 * 4;

  hipMemsetAsync(lossP, 0, NQ * 256 * sizeof(float), stream);
  cb_prep_kernel<<<NQ * KCB / 8, 256, 0, stream>>>(cbs, Bt, hcS);
  init_kernel<<<NTOK / 8, 256, 0, stream>>>(x, At);

  for (int q = 0; q < NQ; ++q) {
    const float* cb = cbs + (size_t)q * KCB * DIMD;
    argmin_kernel<<<512, 256, 0, stream>>>(At, Bt + (size_t)q * KCB * DIMD,
                                           hcS + (size_t)q * KCB, part);
    const int last = (q == NQ - 1);
    post_kernel<<<NTOK / 4, 256, 0, stream>>>(
        part, q == 0 ? x : res, res, x, cb, out, At,
        idxf + (size_t)q * NTOK, lossP + (size_t)q * 256,
        /*writeRes=*/!last, /*emit=*/!last, /*writeOut=*/last);
  }
  finalize_kernel<<<1, 256, 0, stream>>>(lossP, losses);
}

// Round 11
// 486.943 us; speedup vs baseline: 2.3396x; 1.0887x over previous
//
#include <hip/hip_runtime.h>
#include <cstdint>

#define DIMD 256
#define KCB  4096
#define NQ   4
#define NTOK 32768   // 8 * 4096

typedef __attribute__((ext_vector_type(8))) _Float16 half8;
typedef __attribute__((ext_vector_type(4))) _Float16 half4;
typedef __attribute__((ext_vector_type(4))) float f32x4;

// ---------------------------------------------------------------- helpers
__device__ __forceinline__ f32x4 mfma16(half8 a, half8 b, f32x4 c) {
  return __builtin_amdgcn_mfma_f32_16x16x32_f16(a, b, c, 0, 0, 0);
}

// ---------------------------------------------------------------- prep
// At is ROW-MAJOR fp16 [NTOK][256]: init and post's emit are fully
// coalesced; argmin does the MFMA fragment gather on its once-per-kernel
// A-load (amortized over 64 tiles).
__global__ void init_kernel(const float* __restrict__ x,
                            _Float16* __restrict__ At) {
  const int tid = threadIdx.x;
  const int n = blockIdx.x * 8 + (tid >> 5);
  const int t = tid & 31;
  const size_t base = (size_t)n * DIMD + t * 8;
  const float4 v0 = *(const float4*)&x[base];
  const float4 v1 = *(const float4*)&x[base + 4];
  const float f[8] = {v0.x, v0.y, v0.z, v0.w, v1.x, v1.y, v1.z, v1.w};
  half8 h;
  #pragma unroll
  for (int j = 0; j < 8; ++j) h[j] = (_Float16)f[j];
  *(half8*)&At[base] = h;
}

// B plane frag-linear, 64-col-chunk-major (one 64-col chunk = contiguous 32 KB):
// frag f = ((c>>6)*8 + kc)*4 + ((c>>4)&3); half = (f*64 + q*16 + (c&15))*8 + j.
// hcS[c] = 512 + 0.5*|cb_c|^2  (argmin key offset; d' = hcS - dot > 0 always).
__global__ void cb_prep_kernel(const float* __restrict__ cbs,
                               _Float16* __restrict__ Bt,
                               float* __restrict__ hcS) {
  const int tid = threadIdx.x;
  const int R = blockIdx.x * 8 + (tid >> 5);   // layer*4096 + code
  const int layer = R >> 12, c = R & 4095;
  const int t = tid & 31;
  const size_t base = (size_t)R * DIMD + t * 8;
  const float4 v0 = *(const float4*)&cbs[base];
  const float4 v1 = *(const float4*)&cbs[base + 4];
  const float f[8] = {v0.x, v0.y, v0.z, v0.w, v1.x, v1.y, v1.z, v1.w};
  half8 h;
  float s = 0.f;
  #pragma unroll
  for (int j = 0; j < 8; ++j) { h[j] = (_Float16)f[j]; s += f[j] * f[j]; }
  const int kc = t >> 2, q = t & 3;
  _Float16* BtL = Bt + (size_t)layer * KCB * DIMD;
  const int fr = ((c >> 6) * 8 + kc) * 4 + ((c >> 4) & 3);
  *(half8*)&BtL[((size_t)fr * 64 + q * 16 + (c & 15)) * 8] = h;
  #pragma unroll
  for (int off = 16; off > 0; off >>= 1) s += __shfl_down(s, off, 32);
  if (t == 0) hcS[R] = 512.0f + 0.5f * s;
}

// ---------------------------------------------------------------- argmin
// ONE-WAVE workgroups: 64 threads = 1 wave = 64 rows x 1024 cols; grid =
// 512 rowgroups x 4 colQ = 2048 blocks -> 8 independent single-wave blocks
// per CU. Rationale: all six prior structures pinned at MfmaUtil 33-40%
// with OccupancyPercent ~18.7% (= 0.75 x the nominal 25% for 8 waves/CU;
// counter calibrated vs round 4's 46%/16-wave). With grid == exact capacity
// and 4-wave blocks, per-block runtime variance leaves wave-slots idle.
// 1-wave blocks remove the barrier entirely and let the CU's 8 wave slots
// drain/refill independently. Inner loop = round-6 body (best measured):
// A resident in regs, B streamed from L2 with p/q half-tile depth-1
// pipeline, keys inline. Ledger: a=128(AGPR) + p/q=32 + acc=16 + u=32 +
// misc ~15 -> ~223 of 256 @ 2 waves/SIMD.
__device__ __forceinline__ void upd_keys(const f32x4 (&acc)[4], int tl,
                                         const float* __restrict__ hcs, int ln,
                                         uint32_t* __restrict__ u1,
                                         uint32_t* __restrict__ u2) {
  const float hcv = hcs[tl * 16 + ln];
  #pragma unroll
  for (int rt = 0; rt < 4; ++rt)
    #pragma unroll
    for (int reg = 0; reg < 4; ++reg) {
      const uint32_t k =
          (__float_as_uint(hcv - acc[rt][reg]) & 0xFFFFFFC0u) | (uint32_t)tl;
      const int s = rt * 4 + reg;
      const uint32_t mx = u1[s] > k ? u1[s] : k;
      u1[s] = u1[s] < k ? u1[s] : k;
      u2[s] = u2[s] < mx ? u2[s] : mx;
    }
}

__global__ __launch_bounds__(64, 2) void argmin_kernel(
    const _Float16* __restrict__ At,     // row-major [NTOK][256]
    const _Float16* __restrict__ Bt,     // layer base (chunk-major frag-linear)
    const float* __restrict__ hcS,       // layer base
    uint2* __restrict__ part)            // [NTOK][4] best-2 col indices
{
  __shared__ float hcs[1024];

  const int lane = threadIdx.x;              // 1 wave per block
  const int rg   = blockIdx.x & 511;         // 512 rowgroups of 64 rows
  const int colQ = blockIdx.x >> 9;
  const int quad = lane >> 4, ln = lane & 15;

  // stage hcS quarter to LDS (1024 floats; 4 x float4 per lane).
  // Same-wave ds_write -> ds_read: in-order, compiler inserts lgkmcnt.
  #pragma unroll
  for (int i = 0; i < 4; ++i)
    *(float4*)&hcs[i * 256 + lane * 4] =
        *(const float4*)&hcS[colQ * 1024 + i * 256 + lane * 4];

  // upfront A fragment gather from row-major At:
  // a[rt][kc][j] = A[row (rg*4+rt)*16+ln][kc*32 + quad*8 + j]
  half8 a[4][8];
  #pragma unroll
  for (int kc = 0; kc < 8; ++kc)
    #pragma unroll
    for (int rt = 0; rt < 4; ++rt)
      a[rt][kc] = *(const half8*)&At[((size_t)(rg * 4 + rt) * 16 + ln) * DIMD +
                                     kc * 32 + quad * 8];

  // best-2 keys per element (16 rows/lane): key = trunc6(as_uint(d')) | tile
  uint32_t u1[16], u2[16];
  #pragma unroll
  for (int s = 0; s < 16; ++s) { u1[s] = 0xFFFFFFFFu; u2[s] = 0xFFFFFFFFu; }

  // quarter base: colQ*1024 cols * 256 d = colQ * 262144 halves
  const _Float16* Bq = Bt + (size_t)colQ * 262144 + lane * 8;
  // frag address for (tile t, kc): ((t>>2)*8 + kc)*4 + (t&3), 512 halves each
  #define BFRAG(t, kc) \
    (*(const half8*)&Bq[(size_t)((((t) >> 2) * 8 + (kc)) * 4 + ((t) & 3)) * 512])

  half8 p[4], q[4];
  #pragma unroll
  for (int k = 0; k < 4; ++k) p[k] = BFRAG(0, k);
  #pragma unroll
  for (int k = 0; k < 4; ++k) q[k] = BFRAG(0, 4 + k);

  f32x4 acc[4];
  const f32x4 z = {0.f, 0.f, 0.f, 0.f};

  for (int t = 0; t < 64; ++t) {
    const int tn = (t + 1) & 63;   // wrap keeps addresses valid; t=63 reload is dead
    __builtin_amdgcn_s_setprio(1);
    // consume p (kc 0..3)
    acc[0] = mfma16(a[0][0], p[0], z);
    acc[1] = mfma16(a[1][0], p[0], z);
    acc[2] = mfma16(a[2][0], p[0], z);
    acc[3] = mfma16(a[3][0], p[0], z);
    #pragma unroll
    for (int rt = 0; rt < 4; ++rt) acc[rt] = mfma16(a[rt][1], p[1], acc[rt]);
    #pragma unroll
    for (int rt = 0; rt < 4; ++rt) acc[rt] = mfma16(a[rt][2], p[2], acc[rt]);
    #pragma unroll
    for (int rt = 0; rt < 4; ++rt) acc[rt] = mfma16(a[rt][3], p[3], acc[rt]);
    __builtin_amdgcn_s_setprio(0);
    // refill p <- tile tn half 0 (covered by q-consume + keys)
    #pragma unroll
    for (int k = 0; k < 4; ++k) p[k] = BFRAG(tn, k);
    __builtin_amdgcn_s_setprio(1);
    // consume q (kc 4..7)
    #pragma unroll
    for (int rt = 0; rt < 4; ++rt) acc[rt] = mfma16(a[rt][4], q[0], acc[rt]);
    #pragma unroll
    for (int rt = 0; rt < 4; ++rt) acc[rt] = mfma16(a[rt][5], q[1], acc[rt]);
    #pragma unroll
    for (int rt = 0; rt < 4; ++rt) acc[rt] = mfma16(a[rt][6], q[2], acc[rt]);
    #pragma unroll
    for (int rt = 0; rt < 4; ++rt) acc[rt] = mfma16(a[rt][7], q[3], acc[rt]);
    __builtin_amdgcn_s_setprio(0);
    // refill q <- tile tn half 1 (covered by keys + next p-consume)
    #pragma unroll
    for (int k = 0; k < 4; ++k) q[k] = BFRAG(tn, 4 + k);
    // best-2 key update for tile t
    upd_keys(acc, t, hcs, ln, u1, u2);
  }
  #undef BFRAG

  // flush: reconstruct cols, merge best-2 across the 16 ln lanes, write part
  #pragma unroll
  for (int s = 0; s < 16; ++s) {
    uint32_t k1 = u1[s], k2 = u2[s];
    int c1 = colQ * 1024 + (int)(k1 & 63u) * 16 + ln;
    int c2 = colQ * 1024 + (int)(k2 & 63u) * 16 + ln;
    #pragma unroll
    for (int m = 1; m <= 8; m <<= 1) {
      const uint32_t o1 = (uint32_t)__shfl_xor((int)k1, m, 64);
      const int      oc1 = __shfl_xor(c1, m, 64);
      const uint32_t o2 = (uint32_t)__shfl_xor((int)k2, m, 64);
      const int      oc2 = __shfl_xor(c2, m, 64);
      const bool t1 = k1 <= o1;
      const uint32_t am = t1 ? o1 : k1; const int amc = t1 ? oc1 : c1;
      k1 = t1 ? k1 : o1;                c1 = t1 ? c1 : oc1;
      const bool t2 = k2 <= o2;
      const uint32_t bm = t2 ? k2 : o2; const int bmc = t2 ? c2 : oc2;
      const bool t3 = am <= bm;
      k2 = t3 ? am : bm;                c2 = t3 ? amc : bmc;
    }
    if (ln == 0) {
      const int rt = s >> 2, reg = s & 3;
      const int row = rg * 64 + rt * 16 + quad * 4 + reg;
      part[(size_t)row * 4 + colQ] = make_uint2((uint32_t)c1, (uint32_t)c2);
    }
  }
}

// ------------------------- fused fp32 rescore (8 cands) + STE update + loss
// Residual identity: res_final = x - sum(stv) exactly, so `out` is written
// only at the last layer as out = x - nr (fp diff vs ref sum order ~2e-6).
// Rescore in fp32 diff-square-sum (more accurate than reference's expanded
// |x|^2-2xc+|c|^2 fp32 formula; near-tie behavior ~= the previous fp64
// version at half the VALU cost -- fp64 wave64 ops were ~20 us/dispatch).
__global__ void post_kernel(const uint2* __restrict__ part,
                            const float* __restrict__ rsrc,  // x (q=0) or res
                            float* __restrict__ rdst,        // res
                            const float* __restrict__ xin,   // x (last layer)
                            const float* __restrict__ cb,    // layer fp32
                            float* __restrict__ out,
                            _Float16* __restrict__ At,       // row-major
                            float* __restrict__ idxf,
                            float* __restrict__ lossP,       // 256 slots
                            int writeRes, int emit, int writeOut) {
  __shared__ float ls[4];
  const int lane = threadIdx.x & 63;
  const int rsub = threadIdx.x >> 6;
  const int row = blockIdx.x * 4 + rsub;

  // lane-parallel rescore: cand id = lane>>3 (direct per-lane load, no
  // runtime-indexed local array), contiguous chunk = (lane&7)*16 B
  const int cd = lane >> 3, dg = lane & 7;
  const int myc = (int)((const uint32_t*)part)[(size_t)row * 8 + cd];
  const float* rrow = rsrc + (size_t)row * DIMD;
  const float* qrow = cb + (size_t)myc * DIMD;
  float d = 0.f;
  #pragma unroll
  for (int k = 0; k < 8; ++k) {
    const int dd = k * 32 + dg * 4;
    const float4 rv = *(const float4*)&rrow[dd];
    const float4 qv = *(const float4*)&qrow[dd];
    const float t0 = rv.x - qv.x;
    const float t1 = rv.y - qv.y;
    const float t2 = rv.z - qv.z;
    const float t3 = rv.w - qv.w;
    d += t0 * t0 + t1 * t1 + t2 * t2 + t3 * t3;
  }
  #pragma unroll
  for (int m = 1; m <= 4; m <<= 1) d += __shfl_xor(d, m, 64);
  float bd = d; int bc = myc;
  #pragma unroll
  for (int m = 8; m <= 32; m <<= 1) {
    const float od = __shfl_xor(bd, m, 64);
    const int   oc = __shfl_xor(bc, m, 64);
    if (od < bd || (od == bd && oc < bc)) { bd = od; bc = oc; }
  }
  const int win = bc;

  // STE update (reference rounding)
  const size_t base = (size_t)row * DIMD + lane * 4;
  const float4 r4 = *(const float4*)&rsrc[base];
  const float4 q4 = *(const float4*)&cb[(size_t)win * DIMD + lane * 4];
  const float rr[4] = {r4.x, r4.y, r4.z, r4.w};
  const float qq[4] = {q4.x, q4.y, q4.z, q4.w};
  float nr[4];
  float s2 = 0.f;
  #pragma unroll
  for (int j = 0; j < 4; ++j) {
    const float stv = rr[j] + (qq[j] - rr[j]);
    nr[j] = rr[j] - stv;
    const float dl = rr[j] - qq[j];
    s2 += dl * dl;
  }
  if (writeRes)
    *(float4*)&rdst[base] = make_float4(nr[0], nr[1], nr[2], nr[3]);
  if (writeOut) {
    const float4 xv = *(const float4*)&xin[base];
    *(float4*)&out[base] =
        make_float4(xv.x - nr[0], xv.y - nr[1], xv.z - nr[2], xv.w - nr[3]);
  }
  if (emit) {
    // row-major At: fully coalesced half4 store
    half4 h;
    #pragma unroll
    for (int j = 0; j < 4; ++j) h[j] = (_Float16)nr[j];
    *(half4*)&At[base] = h;
  }
  if (lane == 0) idxf[row] = (float)win;

  #pragma unroll
  for (int m = 1; m < 64; m <<= 1) s2 += __shfl_xor(s2, m, 64);
  if (lane == 0) ls[rsub] = s2;
  __syncthreads();
  if (threadIdx.x == 0) {
    const float tot = ls[0] + ls[1] + ls[2] + ls[3];
    atomicAdd(&lossP[blockIdx.x & 255],
              tot * (1.0f / (float)((size_t)NTOK * DIMD)));
  }
}

// sum 4 x 256 loss partials -> losses[4]
__global__ void finalize_kernel(const float* __restrict__ lossP,
                                float* __restrict__ losses) {
  const int w = threadIdx.x >> 6, lane = threadIdx.x & 63;
  float s = lossP[w * 256 + lane] + lossP[w * 256 + 64 + lane] +
            lossP[w * 256 + 128 + lane] + lossP[w * 256 + 192 + lane];
  #pragma unroll
  for (int m = 1; m < 64; m <<= 1) s += __shfl_xor(s, m, 64);
  if (lane == 0) losses[w] = s;
}

// ---------------------------------------------------------------- launch
extern "C" void kernel_launch(void* const* d_in, const int* in_sizes, int n_in,
                              void* d_out, int out_size, void* d_ws, size_t ws_size,
                              hipStream_t stream) {
  const float* x   = (const float*)d_in[0];   // [8,4096,256]
  const float* cbs = (const float*)d_in[1];   // [4,4096,256]

  float* out    = (float*)d_out;
  float* idxf   = out + (size_t)NTOK * DIMD;
  float* losses = idxf + (size_t)NQ * NTOK;

  char* wsp = (char*)d_ws;
  float* res = (float*)wsp;                    wsp += (size_t)NTOK * DIMD * 4;      // 32 MB
  _Float16* At = (_Float16*)wsp;               wsp += (size_t)NTOK * DIMD * 2;      // 16 MB
  _Float16* Bt = (_Float16*)wsp;               wsp += (size_t)NQ * KCB * DIMD * 2;  //  8 MB
  float* hcS = (float*)wsp;                    wsp += (size_t)NQ * KCB * 4;
  uint2* part = (uint2*)wsp;                   wsp += (size_t)NTOK * 4 * 8;
  float* lossP = (float*)wsp;                  wsp += (size_t)NQ * 256 * 4;

  hipMemsetAsync(lossP, 0, NQ * 256 * sizeof(float), stream);
  cb_prep_kernel<<<NQ * KCB / 8, 256, 0, stream>>>(cbs, Bt, hcS);
  init_kernel<<<NTOK / 8, 256, 0, stream>>>(x, At);

  for (int q = 0; q < NQ; ++q) {
    const float* cb = cbs + (size_t)q * KCB * DIMD;
    argmin_kernel<<<2048, 64, 0, stream>>>(At, Bt + (size_t)q * KCB * DIMD,
                                           hcS + (size_t)q * KCB, part);
    const int last = (q == NQ - 1);
    post_kernel<<<NTOK / 4, 256, 0, stream>>>(
        part, q == 0 ? x : res, res, x, cb, out, At,
        idxf + (size_t)q * NTOK, lossP + (size_t)q * 256,
        /*writeRes=*/!last, /*emit=*/!last, /*writeOut=*/last);
  }
  finalize_kernel<<<1, 256, 0, stream>>>(lossP, losses);
}